// Round 11
// baseline (209.820 us; speedup 1.0000x reference)
//
#include <hip/hip_runtime.h>
#include <hip/hip_bf16.h>
#include <math.h>

// B=8, P=1024, DIM=768, H=12, KV=6, GS=2, HD=64
// R21: attn split-K across waves. No-max softmax partials are purely
// ADDITIVE (fixed m=0: O = sum exp2(s)V, l = sum exp2(s)) -> block = 4
// waves as 2 qgroups x 2 kgroups (4 K-tiles each, half the serial chain),
// K-pairs merge O/l through LDS. Grid 768->1536, P_lds per-wave 16-row
// buffer (qn sequential) = 17.4KB. Plus v_perm-based RNE pair pack
// (~5 ops vs ~11, bit-identical) in the shared helper (attn/prep/stats2).
// GEMMs FB-layout (R20-proven) frozen.

#define NTHREADS 256

typedef __bf16 bf16x8 __attribute__((ext_vector_type(8)));
typedef float f32x4 __attribute__((ext_vector_type(4)));

#define MFMA16(a, b, c) __builtin_amdgcn_mfma_f32_16x16x32_bf16(a, b, c, 0, 0, 0)

// q scale with log2(e) folded: softmax exp(x) == exp2(x') for pre-scaled logits
#define QSCALE 0.18033688011112042f   // 0.125 * 1.4426950408889634

__device__ __forceinline__ float fexp2(float x) {
#if __has_builtin(__builtin_amdgcn_exp2f)
    return __builtin_amdgcn_exp2f(x);
#else
    return __expf(x * 0.6931471805599453f);
#endif
}

__device__ __forceinline__ void gload16(const void* g, void* l) {
    __builtin_amdgcn_global_load_lds(
        (const __attribute__((address_space(1))) void*)g,
        (__attribute__((address_space(3))) void*)l, 16, 0, 0);
}

// ---------------- Threefry-2x32 partitionable, key=(0,42) --------------------
__device__ __forceinline__ unsigned rotl_u32(unsigned x, int r) {
    return (x << r) | (x >> (32 - r));
}
__device__ __forceinline__ void threefry_0_42(unsigned x0, unsigned x1,
                                              unsigned& o0, unsigned& o1) {
    const unsigned ks0 = 0u, ks1 = 42u, ks2 = 0u ^ 42u ^ 0x1BD11BDAu;
    x0 += ks0; x1 += ks1;
#define R4(a,b,c,d) \
    x0 += x1; x1 = rotl_u32(x1,a); x1 ^= x0; \
    x0 += x1; x1 = rotl_u32(x1,b); x1 ^= x0; \
    x0 += x1; x1 = rotl_u32(x1,c); x1 ^= x0; \
    x0 += x1; x1 = rotl_u32(x1,d); x1 ^= x0;
    R4(13,15,26,6)   x0 += ks1; x1 += ks2 + 1u;
    R4(17,29,16,24)  x0 += ks2; x1 += ks0 + 2u;
    R4(13,15,26,6)   x0 += ks0; x1 += ks1 + 3u;
    R4(17,29,16,24)  x0 += ks1; x1 += ks2 + 4u;
    R4(13,15,26,6)   x0 += ks2; x1 += ks0 + 5u;
#undef R4
    o0 = x0; o1 = x1;
}
__device__ __forceinline__ float tf_uniform(unsigned i) {
    unsigned o0, o1;
    threefry_0_42(0u, i, o0, o1);
    unsigned bits = o0 ^ o1;
    return __uint_as_float((bits >> 9) | 0x3f800000u) - 1.0f;
}

__device__ __forceinline__ float wave_sum64(float v) {
#pragma unroll
    for (int off = 32; off; off >>= 1) v += __shfl_xor(v, off, 64);
    return v;
}

__device__ __forceinline__ unsigned short bf16_rne(float x) {
    unsigned u = __float_as_uint(x);
    return (unsigned short)((u + 0x7fffu + ((u >> 16) & 1u)) >> 16);
}
// RNE pair-pack via v_perm_b32: bit-identical to 2x bf16_rne, ~half the ops.
__device__ __forceinline__ unsigned pack_bf16x2(float lo, float hi) {
    unsigned ul = __float_as_uint(lo), uh = __float_as_uint(hi);
    unsigned rl = ul + 0x7fffu + ((ul >> 16) & 1u);
    unsigned rh = uh + 0x7fffu + ((uh >> 16) & 1u);
    return __builtin_amdgcn_perm(rh, rl, 0x07060302u);
}
__device__ __forceinline__ float bfu(unsigned v) {
    return __uint_as_float(v << 16);
}

// FB layout: element (row, col) of a [R x 768] matrix lives at
//   ((kc*NC + row/16)*2 + kh)*512 + (g*16 + row%16)*8 + e
// with kc=col/64, kin=col%64, kh=kin/32, g=(kin/8)%4, e=col%8, NC=R/16.
// This equals the LDS staging image, so a K-step tile is contiguous.

// ---------------- prep: cast_x | z1(bf16) | cast_w fused ---------------------
// blocks [0,1536): x->bf16 FB; [1536,1920): Z; [1920,2352): W casts FB.
__global__ __launch_bounds__(NTHREADS) void prep_k(
    const float* __restrict__ x, const float* __restrict__ Wq,
    const float* __restrict__ Wk, const float* __restrict__ Wv,
    const float* __restrict__ Wp,
    unsigned short* __restrict__ xb, unsigned short* __restrict__ wstk,
    unsigned short* __restrict__ wpt,
    unsigned short* __restrict__ zb, float* __restrict__ zpart)
{
    __shared__ float rbuf[8];
    int blk = blockIdx.x;
    if (blk < 1536) {
#pragma unroll
        for (int j = 0; j < 4; ++j) {
            int i = blk * 1024 + j * 256 + threadIdx.x;
            float4 v = ((const float4*)x)[i];
            uint2 u;
            u.x = pack_bf16x2(v.x, v.y);
            u.y = pack_bf16x2(v.z, v.w);
            int f0 = i * 4;
            int row = f0 / 768, col = f0 - row * 768;
            int kc = col >> 6, kin = col & 63;
            int kh = kin >> 5, g = (kin >> 3) & 3, e = col & 7;   // e in {0,4}
            int chunk = row >> 4, cl = row & 15;
            size_t a = (((size_t)(kc * 512 + chunk)) * 2 + kh) * 512
                       + (g * 16 + cl) * 8 + e;
            *(uint2*)&xb[a] = u;
        }
    } else if (blk < 1920) {
        int zc = blk - 1536;
        int row = zc >> 5, chunk = zc & 31;
        int g = row & 1;
        int j0 = chunk * 2048;
        float sum = 0.f, sumsq = 0.f;
        for (int t = threadIdx.x; t < 2048; t += NTHREADS) {
            int j = j0 + t;
            unsigned i = (unsigned)row * 65536u + (unsigned)j;
            float m = tf_uniform(i);
            if (j == g) m = 0.f;
            zb[i] = bf16_rne(m);
            sum += m; sumsq += m * m;
        }
        sum = wave_sum64(sum); sumsq = wave_sum64(sumsq);
        int lane = threadIdx.x & 63, wv = threadIdx.x >> 6;
        if (lane == 0) { rbuf[wv] = sum; rbuf[4 + wv] = sumsq; }
        __syncthreads();
        if (threadIdx.x == 0) {
            zpart[zc * 2]     = rbuf[0] + rbuf[1] + rbuf[2] + rbuf[3];
            zpart[zc * 2 + 1] = rbuf[4] + rbuf[5] + rbuf[6] + rbuf[7];
        }
    } else {
        int id = blk - 1920;
        const float* W; unsigned short* dstbuf; int N, rowbase, NC;
        if (id < 144)      { W = Wq; dstbuf = wstk; N = 768; rowbase = 0;    NC = 96; }
        else if (id < 216) { W = Wk; dstbuf = wstk; N = 384; rowbase = 768;  NC = 96; id -= 144; }
        else if (id < 288) { W = Wv; dstbuf = wstk; N = 384; rowbase = 1152; NC = 96; id -= 216; }
        else               { W = Wp; dstbuf = wpt;  N = 768; rowbase = 0;    NC = 48; id -= 288; }
        int ntn = N >> 6;
        int kt = id / ntn, nt = id % ntn;
        int k0 = kt * 64, n0 = nt * 64;
        int t = threadIdx.x;
        int tn = t & 63, tk = t >> 6;
        float r[16];
#pragma unroll
        for (int j = 0; j < 16; ++j)
            r[j] = W[(size_t)(k0 + tk * 16 + j) * N + n0 + tn];
        uint4 u0, u1;
        u0.x = pack_bf16x2(r[0], r[1]);   u0.y = pack_bf16x2(r[2], r[3]);
        u0.z = pack_bf16x2(r[4], r[5]);   u0.w = pack_bf16x2(r[6], r[7]);
        u1.x = pack_bf16x2(r[8], r[9]);   u1.y = pack_bf16x2(r[10], r[11]);
        u1.z = pack_bf16x2(r[12], r[13]); u1.w = pack_bf16x2(r[14], r[15]);
        // FB write: u0 = cols k0+tk*16+0..7 (g0), u1 = +8..15 (g0+1)
        int rowg = rowbase + n0 + tn;
        int chunk = rowg >> 4, cl = rowg & 15;
        int kc = k0 >> 6;
        int kh = tk >> 1, g0 = (tk & 1) * 2;
        size_t base = (((size_t)(kc * NC + chunk)) * 2 + kh) * 512 + cl * 8;
        *(uint4*)&dstbuf[base + g0 * 128]       = u0;
        *(uint4*)&dstbuf[base + (g0 + 1) * 128] = u1;
    }
}

// ---------------- bf16 MFMA GEMM core: 128x256 tile, BK=64, FB inputs --------
__device__ __forceinline__ void mfma_tile128x256(
    const unsigned short* __restrict__ Afb, int nca,
    const unsigned short* __restrict__ Bfb,
    int row0, int col0,
    unsigned short* As, unsigned short* Bs, f32x4 acc[4][4])
{
    const int tid = threadIdx.x;
    const int lane = tid & 63, w = tid >> 6;
    const int c = lane & 15, g = lane >> 4;
    const int wm = w & 1, wn = w >> 1;   // 2 x 4 wave grid

#pragma unroll
    for (int mi = 0; mi < 4; ++mi)
#pragma unroll
        for (int ni = 0; ni < 4; ++ni) acc[mi][ni] = (f32x4){0.f, 0.f, 0.f, 0.f};

    const unsigned short* Abase = Afb + (size_t)(row0 >> 4) * 1024;
    const unsigned short* Bbase = Bfb + (size_t)(col0 >> 4) * 1024;

    for (int kc = 0; kc < 12; ++kc) {
        const unsigned short* a = Abase + (size_t)kc * nca * 1024;
        const unsigned short* bb = Bbase + (size_t)kc * 512 * 1024;
        __syncthreads();
        gload16(a  + tid * 8,         As + tid * 8);
        gload16(a  + tid * 8 + 4096,  As + tid * 8 + 4096);
        gload16(bb + tid * 8,         Bs + tid * 8);
        gload16(bb + tid * 8 + 4096,  Bs + tid * 8 + 4096);
        gload16(bb + tid * 8 + 8192,  Bs + tid * 8 + 8192);
        gload16(bb + tid * 8 + 12288, Bs + tid * 8 + 12288);
        __syncthreads();
#pragma unroll
        for (int ks = 0; ks < 2; ++ks) {
            bf16x8 aA[4], bB[4];
#pragma unroll
            for (int mi = 0; mi < 4; ++mi)
                aA[mi] = *(const bf16x8*)&As[(wm * 4 + mi) * 1024 + ks * 512 + g * 128 + c * 8];
#pragma unroll
            for (int ni = 0; ni < 4; ++ni)
                bB[ni] = *(const bf16x8*)&Bs[(wn * 4 + ni) * 1024 + ks * 512 + g * 128 + c * 8];
#pragma unroll
            for (int mi = 0; mi < 4; ++mi)
#pragma unroll
                for (int ni = 0; ni < 4; ++ni)
                    acc[mi][ni] = MFMA16(aA[mi], bB[ni], acc[mi][ni]);
        }
    }
}

// qkv fused: A = stacked FB weights (1536x768, NC=96), B = xb FB.
// Grid 384 = 8 XCD x (4 col-panels x 12 row-tiles).
__global__ __launch_bounds__(512) void qkv_mfma_k(
    const unsigned short* __restrict__ xb, const unsigned short* __restrict__ wstk,
    unsigned short* __restrict__ qbh, unsigned short* __restrict__ kb2,
    unsigned short* __restrict__ vb2)
{
    __shared__ unsigned short As[8192];   // 16KB
    __shared__ unsigned short Bs[16384];  // 32KB
    int id = blockIdx.x;
    int xcd = id & 7, slot = id >> 3;        // slot 0..47
    int col0i = xcd + ((slot & 3) << 3);     // 0..31
    int row0i = slot >> 2;                   // 0..11
    int row0 = row0i * 128, col0 = col0i * 256;
    f32x4 acc[4][4];
    mfma_tile128x256(wstk, 96, xb, row0, col0, As, Bs, acc);

    const int tid = threadIdx.x;
    const int w = tid >> 6, lane = tid & 63;
    const int c = lane & 15, g = lane >> 4;
    const int wm = w & 1, wn = w >> 1;

#pragma unroll
    for (int mi = 0; mi < 4; ++mi) {
        int ocb = row0 + wm * 64 + mi * 16;      // 16-row block base (uniform)
        int ocol = ocb + g * 4;                  // + r in ushort4 components
#pragma unroll
        for (int ni = 0; ni < 4; ++ni) {
            int pglob = col0 + wn * 64 + ni * 16 + c;
            int b = pglob >> 10, pin = pglob & 1023;
            if (ocb < 768) {
                // ---- q ----
                ushort4 u;
                u.x = bf16_rne(acc[mi][ni][0] * QSCALE);
                u.y = bf16_rne(acc[mi][ni][1] * QSCALE);
                u.z = bf16_rne(acc[mi][ni][2] * QSCALE);
                u.w = bf16_rne(acc[mi][ni][3] * QSCALE);
                int h = ocol >> 6, d0 = ocol & 63;
                *(ushort4*)&qbh[(((size_t)b * 12 + h) * 1024 + pin) * 64 + d0] = u;
            } else if (ocb < 1152) {
                // ---- k ----
                int kcol = ocol - 768;
                int kv = kcol >> 6, d0 = kcol & 63;
                int kt = pin >> 7, key = pin & 127;
                ushort4 u;
                u.x = bf16_rne(acc[mi][ni][0]);
                u.y = bf16_rne(acc[mi][ni][1]);
                u.z = bf16_rne(acc[mi][ni][2]);
                u.w = bf16_rne(acc[mi][ni][3]);
                *(ushort4*)&kb2[((((size_t)(b * 6 + kv) * 8 + kt) * 8 + (d0 >> 3)) * 128
                                 + key) * 8 + (d0 & 7)] = u;
            } else {
                // ---- v (transposed orientation: r spans d -> scalar stores)
                int kt = pin >> 7, pg = (pin & 127) >> 3, p8 = pin & 7;
#pragma unroll
                for (int r = 0; r < 4; ++r) {
                    int vcol = ocol + r - 1152;
                    int kv = vcol >> 6, d = vcol & 63;
                    vb2[((((size_t)(b * 6 + kv) * 8 + kt) * 16 + pg) * 64 + d) * 8 + p8]
                        = bf16_rne(acc[mi][ni][r]);
                }
            }
        }
    }
}

// proj: A = wpt FB (768x768, NC=48), B = attb FB. Grid 192 = 8 x (4 x 6).
__global__ __launch_bounds__(512) void proj_mfma_k(
    const unsigned short* __restrict__ attb, const unsigned short* __restrict__ wpt,
    const float* __restrict__ bp, float* __restrict__ out)
{
    __shared__ unsigned short As[8192];
    __shared__ unsigned short Bs[16384];
    int id = blockIdx.x;
    int xcd = id & 7, slot = id >> 3;        // 0..23
    int col0i = xcd + ((slot & 3) << 3);     // 0..31
    int row0i = slot >> 2;                   // 0..5
    int row0 = row0i * 128, col0 = col0i * 256;
    f32x4 acc[4][4];
    mfma_tile128x256(wpt, 48, attb, row0, col0, As, Bs, acc);

    const int tid = threadIdx.x;
    const int w = tid >> 6, lane = tid & 63;
    const int c = lane & 15, g = lane >> 4;
    const int wm = w & 1, wn = w >> 1;
#pragma unroll
    for (int mi = 0; mi < 4; ++mi) {
        int ocol = row0 + wm * 64 + mi * 16 + g * 4;
        float4 bias = *(const float4*)&bp[ocol];
#pragma unroll
        for (int ni = 0; ni < 4; ++ni) {
            int p = col0 + wn * 64 + ni * 16 + c;
            float4 u;
            u.x = acc[mi][ni][0] + bias.x;
            u.y = acc[mi][ni][1] + bias.y;
            u.z = acc[mi][ni][2] + bias.z;
            u.w = acc[mi][ni][3] + bias.w;
            *(float4*)&out[(size_t)p * 768 + ocol] = u;
        }
    }
}

// ---------------- bf16 MFMA flash attention: split-K 2x2 waves --------------
// Block = 64 q-rows x full 1024 keys: wave w = (qg = w&1, kg = w>>1);
// wave does 4 K-tiles. No-max partials are additive: K-pairs merge O/l via
// LDS. P_lds = per-wave 16-row buffer (qn sequential). Grid 1536,
// XCD-swizzled per (b,kv). attb written in FB layout. Fused stats1.
#define LDP 136
__global__ __launch_bounds__(NTHREADS) void attn_mfma_k(
    const unsigned short* __restrict__ qbh, const unsigned short* __restrict__ kb2,
    const unsigned short* __restrict__ vb2, unsigned short* __restrict__ attb,
    float* __restrict__ spart)
{
    __shared__ unsigned short P_lds[4 * 16 * LDP];   // 17408 B; combine aliases
    __shared__ float lx[2][64][2];
    __shared__ float l_s[2][32];
    __shared__ float sbuf[8];

    int id = blockIdx.x;
    int xcd = id & 7, slot = id >> 3;        // 1536 = 8 * 192
    int grp = slot % 6, member = slot / 6;   // member 0..31
    int g48 = xcd + 8 * grp;                 // 0..47 (b,kv) group
    int b = g48 / 6, kv = g48 % 6;
    int h = kv * 2 + (member & 1);
    int qt64 = member >> 1;                  // 0..15
    const int qt0 = qt64 * 64;

    const int tid = threadIdx.x;
    const int w = tid >> 6, lane = tid & 63;
    const int c = lane & 15, g = lane >> 4;
    const int qg = w & 1, kg = w >> 1;

    const unsigned short* qh = qbh + (((size_t)b * 12 + h) * 1024 + qt0 + qg * 32) * 64;
    const unsigned short* kbase = kb2 + ((size_t)(b * 6 + kv) * 8) * 8192;
    const unsigned short* vbase = vb2 + ((size_t)(b * 6 + kv) * 8) * 8192;
    unsigned short* Pw = P_lds + w * 16 * LDP;

    // Q fragments loop-invariant: hoist
    bf16x8 bQ[2][2];
#pragma unroll
    for (int ks = 0; ks < 2; ++ks) {
        bQ[ks][0] = *(const bf16x8*)(qh + (size_t)(c) * 64 + ks * 32 + g * 8);
        bQ[ks][1] = *(const bf16x8*)(qh + (size_t)(16 + c) * 64 + ks * 32 + g * 8);
    }

    f32x4 O[2][4];
#pragma unroll
    for (int i = 0; i < 2; ++i)
#pragma unroll
        for (int j = 0; j < 4; ++j) O[i][j] = (f32x4){0.f, 0.f, 0.f, 0.f};
    float l_r[2] = {0.f, 0.f};

#pragma unroll 1
    for (int tt = 0; tt < 4; ++tt) {
        int t = kg * 4 + tt;
        const unsigned short* kt = kbase + (size_t)t * 8192;
        const unsigned short* vt = vbase + (size_t)t * 8192;

        // batch-issue all 16 K-fragment loads
        bf16x8 aK[2][8];
#pragma unroll
        for (int ks = 0; ks < 2; ++ks)
#pragma unroll
            for (int mb = 0; mb < 8; ++mb)
                aK[ks][mb] = *(const bf16x8*)(kt + ((size_t)(ks * 4 + g) * 128 + mb * 16 + c) * 8);

        f32x4 S[8][2];
#pragma unroll
        for (int mb = 0; mb < 8; ++mb) {
            S[mb][0] = (f32x4){0.f, 0.f, 0.f, 0.f};
            S[mb][1] = (f32x4){0.f, 0.f, 0.f, 0.f};
        }
#pragma unroll
        for (int ks = 0; ks < 2; ++ks)
#pragma unroll
            for (int mb = 0; mb < 8; ++mb) {
                S[mb][0] = MFMA16(aK[ks][mb], bQ[ks][0], S[mb][0]);
                S[mb][1] = MFMA16(aK[ks][mb], bQ[ks][1], S[mb][1]);
            }

        // batch-issue all 16 V-fragment loads (latency hides under SM)
        bf16x8 bV[4][4];
#pragma unroll
        for (int ks = 0; ks < 4; ++ks)
#pragma unroll
            for (int nb = 0; nb < 4; ++nb)
                bV[ks][nb] = *(const bf16x8*)(vt + ((size_t)(ks * 4 + g) * 64 + nb * 16 + c) * 8);

        // qn-sequential: softmax+pack into 16-row buffer, then PV, twice
#pragma unroll
        for (int qn = 0; qn < 2; ++qn) {
            float lt = 0.f;
#pragma unroll
            for (int mb = 0; mb < 8; ++mb) {
                float p0 = fexp2(S[mb][qn][0]);
                float p1 = fexp2(S[mb][qn][1]);
                float p2 = fexp2(S[mb][qn][2]);
                float p3 = fexp2(S[mb][qn][3]);
                lt += (p0 + p1) + (p2 + p3);
                uint2 uu;
                uu.x = pack_bf16x2(p0, p1);
                uu.y = pack_bf16x2(p2, p3);
                *(uint2*)&Pw[(size_t)c * LDP + mb * 16 + g * 4] = uu;
            }
            lt += __shfl_xor(lt, 16, 64);
            lt += __shfl_xor(lt, 32, 64);
            l_r[qn] += lt;
#pragma unroll
            for (int ks = 0; ks < 4; ++ks) {
                bf16x8 aP = *(const bf16x8*)&Pw[(size_t)c * LDP + ks * 32 + g * 8];
#pragma unroll
                for (int nb = 0; nb < 4; ++nb)
                    O[qn][nb] = MFMA16(aP, bV[ks][nb], O[qn][nb]);
            }
        }
    }

    // ---- K-pair combine (additive): waves kg=1 send O/l to kg=0 ----
    __syncthreads();                       // all P reads done
    float* comb = (float*)P_lds;           // 2 x 64 x 32 f32 = 16KB <= 17408B
    if (w >= 2) {
        int base = ((w - 2) * 64 + lane) * 32;
#pragma unroll
        for (int qn = 0; qn < 2; ++qn)
#pragma unroll
            for (int nb = 0; nb < 4; ++nb)
                *(f32x4*)&comb[base + qn * 16 + nb * 4] = O[qn][nb];
        lx[w - 2][lane][0] = l_r[0];
        lx[w - 2][lane][1] = l_r[1];
    }
    __syncthreads();
    if (w < 2) {
        int base = (w * 64 + lane) * 32;
#pragma unroll
        for (int qn = 0; qn < 2; ++qn)
#pragma unroll
            for (int nb = 0; nb < 4; ++nb)
                O[qn][nb] += *(f32x4*)&comb[base + qn * 16 + nb * 4];
        l_r[0] += lx[w][lane][0];
        l_r[1] += lx[w][lane][1];

        if (g == 0) { l_s[w][c] = l_r[0]; l_s[w][16 + c] = l_r[1]; }
        f32x4 li0 = *(f32x4*)&l_s[w][g * 4];
        f32x4 li1 = *(f32x4*)&l_s[w][16 + g * 4];
        float inv0[4], inv1[4];
#pragma unroll
        for (int r = 0; r < 4; ++r) { inv0[r] = 1.f / li0[r]; inv1[r] = 1.f / li1[r]; }
        // FB attb store: rows (b*1024+qt0+w*32 ..+31); O[0]->rowblk, O[1]->+1
        int rowblk = (b * 1024 + qt0 + w * 32) >> 4;
        float psum = 0.f, psumsq = 0.f;
#pragma unroll
        for (int r = 0; r < 4; ++r) {
            int cl = g * 4 + r;
#pragma unroll
            for (int nb = 0; nb < 4; ++nb) {
                float o0 = O[0][nb][r] * inv0[r];
                float o1 = O[1][nb][r] * inv1[r];
                psum += o0 + o1;
                psumsq += o0 * o0 + o1 * o1;
                int kh = nb >> 1, gb = (nb & 1) * 2 + (c >> 3), e = c & 7;
                size_t a0 = (((size_t)h * 512 + rowblk) * 2 + kh) * 512
                            + (gb * 16 + cl) * 8 + e;
                size_t a1 = (((size_t)h * 512 + rowblk + 1) * 2 + kh) * 512
                            + (gb * 16 + cl) * 8 + e;
                attb[a0] = bf16_rne(o0);
                attb[a1] = bf16_rne(o1);
            }
        }
        psum = wave_sum64(psum); psumsq = wave_sum64(psumsq);
        if (lane == 0) { sbuf[w] = psum; sbuf[4 + w] = psumsq; }
    }
    __syncthreads();
    if (tid == 0) {
        int idx = ((b * 12 + h) * 16 + qt64) * 2;
        spart[idx]     = sbuf[0] + sbuf[1];
        spart[idx + 1] = sbuf[4] + sbuf[5];
    }
}

// ---------------- stats phase 2: att -= M*a - b (attb in FB layout) ----------
__global__ __launch_bounds__(NTHREADS) void stats2_k(
    unsigned short* __restrict__ attb, const unsigned short* __restrict__ zb,
    const float* __restrict__ spart, const float* __restrict__ zpart)
{
    int blk = blockIdx.x;
    int bh = blk >> 3, ch = blk & 7;
    int b = bh / 12, h = bh % 12;
    float zs = 0.f, zs2 = 0.f, rs = 0.f, rs2 = 0.f;
#pragma unroll
    for (int cc = 0; cc < 32; ++cc) {
        zs  += zpart[(h * 32 + cc) * 2];
        zs2 += zpart[(h * 32 + cc) * 2 + 1];
    }
#pragma unroll
    for (int cc = 0; cc < 16; ++cc) {
        rs  += spart[(bh * 16 + cc) * 2];
        rs2 += spart[(bh * 16 + cc) * 2 + 1];
    }
    float m_mean = zs * (1.f / 65536.f);
    float m_var  = (zs2 - 65536.f * m_mean * m_mean) * (1.f / 65535.f);
    float m_sd   = sqrtf(fmaxf(m_var, 0.f));
    if (m_sd == 0.f) m_sd = 1.f;
    float r_mean = rs * (1.f / 65536.f);
    float r_var  = (rs2 - 65536.f * r_mean * r_mean) * (1.f / 65535.f);
    float r_sd   = sqrtf(fmaxf(r_var, 0.f));
    float a = r_sd / m_sd;
    float bc = m_mean * a - r_mean;

    const unsigned short* zrow = zb + (size_t)h * 65536 + (size_t)ch * 8192;
    for (int f = threadIdx.x; f < 1024; f += NTHREADS) {
        int p = f >> 3, dq = (f & 7) * 8;
        int row = b * 1024 + ch * 128 + p;
        int chunk = row >> 4, cl = row & 15;
        int kh = dq >> 5, gb = (dq >> 3) & 3;
        size_t aoff = (((size_t)h * 512 + chunk) * 2 + kh) * 512 + (gb * 16 + cl) * 8;
        unsigned short* ptr = attb + aoff;
        uint4 u = *(const uint4*)ptr;
        uint4 zu = *(const uint4*)(zrow + (size_t)f * 8);
        float v0 = bfu(u.x)       - bfu(zu.x)       * a + bc;
        float v1 = bfu(u.x >> 16) - bfu(zu.x >> 16) * a + bc;
        float v2 = bfu(u.y)       - bfu(zu.y)       * a + bc;
        float v3 = bfu(u.y >> 16) - bfu(zu.y >> 16) * a + bc;
        float v4 = bfu(u.z)       - bfu(zu.z)       * a + bc;
        float v5 = bfu(u.z >> 16) - bfu(zu.z >> 16) * a + bc;
        float v6 = bfu(u.w)       - bfu(zu.w)       * a + bc;
        float v7 = bfu(u.w >> 16) - bfu(zu.w >> 16) * a + bc;
        uint4 o;
        o.x = pack_bf16x2(v0, v1);
        o.y = pack_bf16x2(v2, v3);
        o.z = pack_bf16x2(v4, v5);
        o.w = pack_bf16x2(v6, v7);
        *(uint4*)ptr = o;
    }
}

extern "C" void kernel_launch(void* const* d_in, const int* in_sizes, int n_in,
                              void* d_out, int out_size, void* d_ws, size_t ws_size,
                              hipStream_t stream) {
    const float* x  = (const float*)d_in[0];
    const float* Wq = (const float*)d_in[1];
    const float* Wk = (const float*)d_in[2];
    const float* Wv = (const float*)d_in[3];
    const float* Wp = (const float*)d_in[4];
    const float* bp = (const float*)d_in[5];
    float* out = (float*)d_out;

    float* ws    = (float*)d_ws;
    float* zpart = ws;                    // 768 f (12 rows x 32 chunks x 2)
    float* spart = zpart + 768;           // 3072 f (96 bh x 16 chunks x 2)
    unsigned short* zb   = (unsigned short*)(spart + 3072);  // 786432 us
    unsigned short* xb   = zb + 786432;    // 6291456 (FB, NC=512)
    unsigned short* wstk = xb + 6291456;   // 1179648 (FB stacked q,k,v NC=96)
    unsigned short* wpt  = wstk + 1179648; // 589824  (FB, NC=48)
    unsigned short* qbh  = wpt + 589824;   // 6291456
    unsigned short* kb2  = qbh + 6291456;  // 3145728
    unsigned short* vb2  = kb2 + 3145728;  // 3145728
    unsigned short* attb = vb2 + 3145728;  // 6291456 (FB, NC=512)

    prep_k<<<2352, NTHREADS, 0, stream>>>(x, Wq, Wk, Wv, Wp,
                                          xb, wstk, wpt, zb, zpart);
    qkv_mfma_k<<<384, 512, 0, stream>>>(xb, wstk, qbh, kb2, vb2);
    attn_mfma_k<<<1536, NTHREADS, 0, stream>>>(qbh, kb2, vb2, attb, spart);
    stats2_k<<<768, NTHREADS, 0, stream>>>(attb, zb, spart, zpart);
    proj_mfma_k<<<192, 512, 0, stream>>>(attb, wpt, bp, out);
}

// Round 12
// 188.368 us; speedup vs baseline: 1.1139x; 1.1139x over previous
//
#include <hip/hip_runtime.h>
#include <hip/hip_bf16.h>
#include <math.h>

// B=8, P=1024, DIM=768, H=12, KV=6, GS=2, HD=64
// R22: attn reverted to R20 structure (R21 split-K regressed: combine-buffer
// 32-way bank conflicts, Q duplication, extra barriers -> MfmaUtil 19.5->14.2).
// Kept from R21: v_perm RNE pair-pack (HW-validated bit-identical, ~6 VALU
// fewer per pack). New: LDP 136->140 -- dword row-stride 68≡4 (mod 32) made
// P_lds b128 reads 8-way bank-conflicted (start bank 4(c+g)%32); stride 70≡6
// enumerates all 16 even residues -> uniform 4-way. GEMMs FB (R20) frozen.

#define NTHREADS 256

typedef __bf16 bf16x8 __attribute__((ext_vector_type(8)));
typedef float f32x4 __attribute__((ext_vector_type(4)));

#define MFMA16(a, b, c) __builtin_amdgcn_mfma_f32_16x16x32_bf16(a, b, c, 0, 0, 0)

// q scale with log2(e) folded: softmax exp(x) == exp2(x') for pre-scaled logits
#define QSCALE 0.18033688011112042f   // 0.125 * 1.4426950408889634

__device__ __forceinline__ float fexp2(float x) {
#if __has_builtin(__builtin_amdgcn_exp2f)
    return __builtin_amdgcn_exp2f(x);
#else
    return __expf(x * 0.6931471805599453f);
#endif
}

__device__ __forceinline__ void gload16(const void* g, void* l) {
    __builtin_amdgcn_global_load_lds(
        (const __attribute__((address_space(1))) void*)g,
        (__attribute__((address_space(3))) void*)l, 16, 0, 0);
}

// ---------------- Threefry-2x32 partitionable, key=(0,42) --------------------
__device__ __forceinline__ unsigned rotl_u32(unsigned x, int r) {
    return (x << r) | (x >> (32 - r));
}
__device__ __forceinline__ void threefry_0_42(unsigned x0, unsigned x1,
                                              unsigned& o0, unsigned& o1) {
    const unsigned ks0 = 0u, ks1 = 42u, ks2 = 0u ^ 42u ^ 0x1BD11BDAu;
    x0 += ks0; x1 += ks1;
#define R4(a,b,c,d) \
    x0 += x1; x1 = rotl_u32(x1,a); x1 ^= x0; \
    x0 += x1; x1 = rotl_u32(x1,b); x1 ^= x0; \
    x0 += x1; x1 = rotl_u32(x1,c); x1 ^= x0; \
    x0 += x1; x1 = rotl_u32(x1,d); x1 ^= x0;
    R4(13,15,26,6)   x0 += ks1; x1 += ks2 + 1u;
    R4(17,29,16,24)  x0 += ks2; x1 += ks0 + 2u;
    R4(13,15,26,6)   x0 += ks0; x1 += ks1 + 3u;
    R4(17,29,16,24)  x0 += ks1; x1 += ks2 + 4u;
    R4(13,15,26,6)   x0 += ks2; x1 += ks0 + 5u;
#undef R4
    o0 = x0; o1 = x1;
}
__device__ __forceinline__ float tf_uniform(unsigned i) {
    unsigned o0, o1;
    threefry_0_42(0u, i, o0, o1);
    unsigned bits = o0 ^ o1;
    return __uint_as_float((bits >> 9) | 0x3f800000u) - 1.0f;
}

__device__ __forceinline__ float wave_sum64(float v) {
#pragma unroll
    for (int off = 32; off; off >>= 1) v += __shfl_xor(v, off, 64);
    return v;
}

__device__ __forceinline__ unsigned short bf16_rne(float x) {
    unsigned u = __float_as_uint(x);
    return (unsigned short)((u + 0x7fffu + ((u >> 16) & 1u)) >> 16);
}
// RNE pair-pack via v_perm_b32: bit-identical to 2x bf16_rne (HW-validated
// in R21: absmax unchanged), ~half the VALU ops.
__device__ __forceinline__ unsigned pack_bf16x2(float lo, float hi) {
    unsigned ul = __float_as_uint(lo), uh = __float_as_uint(hi);
    unsigned rl = ul + 0x7fffu + ((ul >> 16) & 1u);
    unsigned rh = uh + 0x7fffu + ((uh >> 16) & 1u);
    return __builtin_amdgcn_perm(rh, rl, 0x07060302u);
}
__device__ __forceinline__ float bfu(unsigned v) {
    return __uint_as_float(v << 16);
}

// FB layout: element (row, col) of a [R x 768] matrix lives at
//   ((kc*NC + row/16)*2 + kh)*512 + (g*16 + row%16)*8 + e
// with kc=col/64, kin=col%64, kh=kin/32, g=(kin/8)%4, e=col%8, NC=R/16.
// This equals the LDS staging image, so a K-step tile is contiguous.

// ---------------- prep: cast_x | z1(bf16) | cast_w fused ---------------------
// blocks [0,1536): x->bf16 FB; [1536,1920): Z; [1920,2352): W casts FB.
__global__ __launch_bounds__(NTHREADS) void prep_k(
    const float* __restrict__ x, const float* __restrict__ Wq,
    const float* __restrict__ Wk, const float* __restrict__ Wv,
    const float* __restrict__ Wp,
    unsigned short* __restrict__ xb, unsigned short* __restrict__ wstk,
    unsigned short* __restrict__ wpt,
    unsigned short* __restrict__ zb, float* __restrict__ zpart)
{
    __shared__ float rbuf[8];
    int blk = blockIdx.x;
    if (blk < 1536) {
#pragma unroll
        for (int j = 0; j < 4; ++j) {
            int i = blk * 1024 + j * 256 + threadIdx.x;
            float4 v = ((const float4*)x)[i];
            uint2 u;
            u.x = pack_bf16x2(v.x, v.y);
            u.y = pack_bf16x2(v.z, v.w);
            int f0 = i * 4;
            int row = f0 / 768, col = f0 - row * 768;
            int kc = col >> 6, kin = col & 63;
            int kh = kin >> 5, g = (kin >> 3) & 3, e = col & 7;   // e in {0,4}
            int chunk = row >> 4, cl = row & 15;
            size_t a = (((size_t)(kc * 512 + chunk)) * 2 + kh) * 512
                       + (g * 16 + cl) * 8 + e;
            *(uint2*)&xb[a] = u;
        }
    } else if (blk < 1920) {
        int zc = blk - 1536;
        int row = zc >> 5, chunk = zc & 31;
        int g = row & 1;
        int j0 = chunk * 2048;
        float sum = 0.f, sumsq = 0.f;
        for (int t = threadIdx.x; t < 2048; t += NTHREADS) {
            int j = j0 + t;
            unsigned i = (unsigned)row * 65536u + (unsigned)j;
            float m = tf_uniform(i);
            if (j == g) m = 0.f;
            zb[i] = bf16_rne(m);
            sum += m; sumsq += m * m;
        }
        sum = wave_sum64(sum); sumsq = wave_sum64(sumsq);
        int lane = threadIdx.x & 63, wv = threadIdx.x >> 6;
        if (lane == 0) { rbuf[wv] = sum; rbuf[4 + wv] = sumsq; }
        __syncthreads();
        if (threadIdx.x == 0) {
            zpart[zc * 2]     = rbuf[0] + rbuf[1] + rbuf[2] + rbuf[3];
            zpart[zc * 2 + 1] = rbuf[4] + rbuf[5] + rbuf[6] + rbuf[7];
        }
    } else {
        int id = blk - 1920;
        const float* W; unsigned short* dstbuf; int N, rowbase, NC;
        if (id < 144)      { W = Wq; dstbuf = wstk; N = 768; rowbase = 0;    NC = 96; }
        else if (id < 216) { W = Wk; dstbuf = wstk; N = 384; rowbase = 768;  NC = 96; id -= 144; }
        else if (id < 288) { W = Wv; dstbuf = wstk; N = 384; rowbase = 1152; NC = 96; id -= 216; }
        else               { W = Wp; dstbuf = wpt;  N = 768; rowbase = 0;    NC = 48; id -= 288; }
        int ntn = N >> 6;
        int kt = id / ntn, nt = id % ntn;
        int k0 = kt * 64, n0 = nt * 64;
        int t = threadIdx.x;
        int tn = t & 63, tk = t >> 6;
        float r[16];
#pragma unroll
        for (int j = 0; j < 16; ++j)
            r[j] = W[(size_t)(k0 + tk * 16 + j) * N + n0 + tn];
        uint4 u0, u1;
        u0.x = pack_bf16x2(r[0], r[1]);   u0.y = pack_bf16x2(r[2], r[3]);
        u0.z = pack_bf16x2(r[4], r[5]);   u0.w = pack_bf16x2(r[6], r[7]);
        u1.x = pack_bf16x2(r[8], r[9]);   u1.y = pack_bf16x2(r[10], r[11]);
        u1.z = pack_bf16x2(r[12], r[13]); u1.w = pack_bf16x2(r[14], r[15]);
        // FB write: u0 = cols k0+tk*16+0..7 (g0), u1 = +8..15 (g0+1)
        int rowg = rowbase + n0 + tn;
        int chunk = rowg >> 4, cl = rowg & 15;
        int kc = k0 >> 6;
        int kh = tk >> 1, g0 = (tk & 1) * 2;
        size_t base = (((size_t)(kc * NC + chunk)) * 2 + kh) * 512 + cl * 8;
        *(uint4*)&dstbuf[base + g0 * 128]       = u0;
        *(uint4*)&dstbuf[base + (g0 + 1) * 128] = u1;
    }
}

// ---------------- bf16 MFMA GEMM core: 128x256 tile, BK=64, FB inputs --------
__device__ __forceinline__ void mfma_tile128x256(
    const unsigned short* __restrict__ Afb, int nca,
    const unsigned short* __restrict__ Bfb,
    int row0, int col0,
    unsigned short* As, unsigned short* Bs, f32x4 acc[4][4])
{
    const int tid = threadIdx.x;
    const int lane = tid & 63, w = tid >> 6;
    const int c = lane & 15, g = lane >> 4;
    const int wm = w & 1, wn = w >> 1;   // 2 x 4 wave grid

#pragma unroll
    for (int mi = 0; mi < 4; ++mi)
#pragma unroll
        for (int ni = 0; ni < 4; ++ni) acc[mi][ni] = (f32x4){0.f, 0.f, 0.f, 0.f};

    const unsigned short* Abase = Afb + (size_t)(row0 >> 4) * 1024;
    const unsigned short* Bbase = Bfb + (size_t)(col0 >> 4) * 1024;

    for (int kc = 0; kc < 12; ++kc) {
        const unsigned short* a = Abase + (size_t)kc * nca * 1024;
        const unsigned short* bb = Bbase + (size_t)kc * 512 * 1024;
        __syncthreads();
        gload16(a  + tid * 8,         As + tid * 8);
        gload16(a  + tid * 8 + 4096,  As + tid * 8 + 4096);
        gload16(bb + tid * 8,         Bs + tid * 8);
        gload16(bb + tid * 8 + 4096,  Bs + tid * 8 + 4096);
        gload16(bb + tid * 8 + 8192,  Bs + tid * 8 + 8192);
        gload16(bb + tid * 8 + 12288, Bs + tid * 8 + 12288);
        __syncthreads();
#pragma unroll
        for (int ks = 0; ks < 2; ++ks) {
            bf16x8 aA[4], bB[4];
#pragma unroll
            for (int mi = 0; mi < 4; ++mi)
                aA[mi] = *(const bf16x8*)&As[(wm * 4 + mi) * 1024 + ks * 512 + g * 128 + c * 8];
#pragma unroll
            for (int ni = 0; ni < 4; ++ni)
                bB[ni] = *(const bf16x8*)&Bs[(wn * 4 + ni) * 1024 + ks * 512 + g * 128 + c * 8];
#pragma unroll
            for (int mi = 0; mi < 4; ++mi)
#pragma unroll
                for (int ni = 0; ni < 4; ++ni)
                    acc[mi][ni] = MFMA16(aA[mi], bB[ni], acc[mi][ni]);
        }
    }
}

// qkv fused: A = stacked FB weights (1536x768, NC=96), B = xb FB.
// Grid 384 = 8 XCD x (4 col-panels x 12 row-tiles).
__global__ __launch_bounds__(512) void qkv_mfma_k(
    const unsigned short* __restrict__ xb, const unsigned short* __restrict__ wstk,
    unsigned short* __restrict__ qbh, unsigned short* __restrict__ kb2,
    unsigned short* __restrict__ vb2)
{
    __shared__ unsigned short As[8192];   // 16KB
    __shared__ unsigned short Bs[16384];  // 32KB
    int id = blockIdx.x;
    int xcd = id & 7, slot = id >> 3;        // slot 0..47
    int col0i = xcd + ((slot & 3) << 3);     // 0..31
    int row0i = slot >> 2;                   // 0..11
    int row0 = row0i * 128, col0 = col0i * 256;
    f32x4 acc[4][4];
    mfma_tile128x256(wstk, 96, xb, row0, col0, As, Bs, acc);

    const int tid = threadIdx.x;
    const int w = tid >> 6, lane = tid & 63;
    const int c = lane & 15, g = lane >> 4;
    const int wm = w & 1, wn = w >> 1;

#pragma unroll
    for (int mi = 0; mi < 4; ++mi) {
        int ocb = row0 + wm * 64 + mi * 16;      // 16-row block base (uniform)
        int ocol = ocb + g * 4;                  // + r in ushort4 components
#pragma unroll
        for (int ni = 0; ni < 4; ++ni) {
            int pglob = col0 + wn * 64 + ni * 16 + c;
            int b = pglob >> 10, pin = pglob & 1023;
            if (ocb < 768) {
                // ---- q ----
                ushort4 u;
                u.x = bf16_rne(acc[mi][ni][0] * QSCALE);
                u.y = bf16_rne(acc[mi][ni][1] * QSCALE);
                u.z = bf16_rne(acc[mi][ni][2] * QSCALE);
                u.w = bf16_rne(acc[mi][ni][3] * QSCALE);
                int h = ocol >> 6, d0 = ocol & 63;
                *(ushort4*)&qbh[(((size_t)b * 12 + h) * 1024 + pin) * 64 + d0] = u;
            } else if (ocb < 1152) {
                // ---- k ----
                int kcol = ocol - 768;
                int kv = kcol >> 6, d0 = kcol & 63;
                int kt = pin >> 7, key = pin & 127;
                ushort4 u;
                u.x = bf16_rne(acc[mi][ni][0]);
                u.y = bf16_rne(acc[mi][ni][1]);
                u.z = bf16_rne(acc[mi][ni][2]);
                u.w = bf16_rne(acc[mi][ni][3]);
                *(ushort4*)&kb2[((((size_t)(b * 6 + kv) * 8 + kt) * 8 + (d0 >> 3)) * 128
                                 + key) * 8 + (d0 & 7)] = u;
            } else {
                // ---- v (transposed orientation: r spans d -> scalar stores)
                int kt = pin >> 7, pg = (pin & 127) >> 3, p8 = pin & 7;
#pragma unroll
                for (int r = 0; r < 4; ++r) {
                    int vcol = ocol + r - 1152;
                    int kv = vcol >> 6, d = vcol & 63;
                    vb2[((((size_t)(b * 6 + kv) * 8 + kt) * 16 + pg) * 64 + d) * 8 + p8]
                        = bf16_rne(acc[mi][ni][r]);
                }
            }
        }
    }
}

// proj: A = wpt FB (768x768, NC=48), B = attb FB. Grid 192 = 8 x (4 x 6).
__global__ __launch_bounds__(512) void proj_mfma_k(
    const unsigned short* __restrict__ attb, const unsigned short* __restrict__ wpt,
    const float* __restrict__ bp, float* __restrict__ out)
{
    __shared__ unsigned short As[8192];
    __shared__ unsigned short Bs[16384];
    int id = blockIdx.x;
    int xcd = id & 7, slot = id >> 3;        // 0..23
    int col0i = xcd + ((slot & 3) << 3);     // 0..31
    int row0i = slot >> 2;                   // 0..5
    int row0 = row0i * 128, col0 = col0i * 256;
    f32x4 acc[4][4];
    mfma_tile128x256(wpt, 48, attb, row0, col0, As, Bs, acc);

    const int tid = threadIdx.x;
    const int w = tid >> 6, lane = tid & 63;
    const int c = lane & 15, g = lane >> 4;
    const int wm = w & 1, wn = w >> 1;
#pragma unroll
    for (int mi = 0; mi < 4; ++mi) {
        int ocol = row0 + wm * 64 + mi * 16 + g * 4;
        float4 bias = *(const float4*)&bp[ocol];
#pragma unroll
        for (int ni = 0; ni < 4; ++ni) {
            int p = col0 + wn * 64 + ni * 16 + c;
            float4 u;
            u.x = acc[mi][ni][0] + bias.x;
            u.y = acc[mi][ni][1] + bias.y;
            u.z = acc[mi][ni][2] + bias.z;
            u.w = acc[mi][ni][3] + bias.w;
            *(float4*)&out[(size_t)p * 768 + ocol] = u;
        }
    }
}

// ---------------- bf16 MFMA flash attention (no-max + batched staging) -------
// R20 structure: 1-D grid 768, XCD-swizzled per (b,kv). No-max softmax
// (R12); K/V batch-staged to regs (R13). LDP=140: P_lds dword row-stride
// 70≡6 (mod 32) -> uniform 4-way banks on b128 reads (was 8-way at 136).
// attb written in FB layout. Fused stats1.
#define LDP 140
__global__ __launch_bounds__(NTHREADS) void attn_mfma_k(
    const unsigned short* __restrict__ qbh, const unsigned short* __restrict__ kb2,
    const unsigned short* __restrict__ vb2, unsigned short* __restrict__ attb,
    float* __restrict__ spart)
{
    __shared__ unsigned short P_lds[4 * 32 * LDP];
    __shared__ float l_s[4][32];
    __shared__ float sbuf[8];

    int id = blockIdx.x;
    int xcd = id & 7, slot = id >> 3;        // 768 = 8 * 96
    int grp = slot % 6, member = slot / 6;   // member 0..15
    int g48 = xcd + 8 * grp;                 // 0..47 (b,kv) group
    int b = g48 / 6, kv = g48 % 6;
    int h = kv * 2 + (member & 1);
    int qtile = member >> 1;                 // 0..7
    const int qt0 = qtile * 128;

    const int tid = threadIdx.x;
    const int w = tid >> 6, lane = tid & 63;
    const int c = lane & 15, g = lane >> 4;

    const unsigned short* qh = qbh + (((size_t)b * 12 + h) * 1024 + qt0 + w * 32) * 64;
    const unsigned short* kbase = kb2 + ((size_t)(b * 6 + kv) * 8) * 8192;
    const unsigned short* vbase = vb2 + ((size_t)(b * 6 + kv) * 8) * 8192;
    unsigned short* Pw = P_lds + w * 32 * LDP;

    // Q fragments are loop-invariant: hoist (4 x bf16x8 = 16 VGPRs)
    bf16x8 bQ[2][2];
#pragma unroll
    for (int ks = 0; ks < 2; ++ks) {
        bQ[ks][0] = *(const bf16x8*)(qh + (size_t)(c) * 64 + ks * 32 + g * 8);
        bQ[ks][1] = *(const bf16x8*)(qh + (size_t)(16 + c) * 64 + ks * 32 + g * 8);
    }

    f32x4 O[2][4];
#pragma unroll
    for (int i = 0; i < 2; ++i)
#pragma unroll
        for (int j = 0; j < 4; ++j) O[i][j] = (f32x4){0.f, 0.f, 0.f, 0.f};
    float l_r[2] = {0.f, 0.f};

    for (int t = 0; t < 8; ++t) {
        const unsigned short* kt = kbase + (size_t)t * 8192;
        const unsigned short* vt = vbase + (size_t)t * 8192;

        // --- phase 1: batch-issue all 16 K-fragment loads ---
        bf16x8 aK[2][8];
#pragma unroll
        for (int ks = 0; ks < 2; ++ks)
#pragma unroll
            for (int mb = 0; mb < 8; ++mb)
                aK[ks][mb] = *(const bf16x8*)(kt + ((size_t)(ks * 4 + g) * 128 + mb * 16 + c) * 8);

        f32x4 S[8][2];
#pragma unroll
        for (int mb = 0; mb < 8; ++mb) {
            S[mb][0] = (f32x4){0.f, 0.f, 0.f, 0.f};
            S[mb][1] = (f32x4){0.f, 0.f, 0.f, 0.f};
        }
        // --- phase 2: QK^T MFMAs from registers ---
#pragma unroll
        for (int ks = 0; ks < 2; ++ks)
#pragma unroll
            for (int mb = 0; mb < 8; ++mb) {
                S[mb][0] = MFMA16(aK[ks][mb], bQ[ks][0], S[mb][0]);
                S[mb][1] = MFMA16(aK[ks][mb], bQ[ks][1], S[mb][1]);
            }

        // --- phase 3: batch-issue all 16 V-fragment loads (hide under SM) ---
        bf16x8 bV[4][4];
#pragma unroll
        for (int ks = 0; ks < 4; ++ks)
#pragma unroll
            for (int nb = 0; nb < 4; ++nb)
                bV[ks][nb] = *(const bf16x8*)(vt + ((size_t)(ks * 4 + g) * 64 + nb * 16 + c) * 8);

        // --- phase 4: no-max softmax + bf16 pack + P->LDS ---
#pragma unroll
        for (int qn = 0; qn < 2; ++qn) {
            float lt = 0.f;
#pragma unroll
            for (int mb = 0; mb < 8; ++mb) {
                float p0 = fexp2(S[mb][qn][0]);
                float p1 = fexp2(S[mb][qn][1]);
                float p2 = fexp2(S[mb][qn][2]);
                float p3 = fexp2(S[mb][qn][3]);
                lt += (p0 + p1) + (p2 + p3);
                uint2 uu;
                uu.x = pack_bf16x2(p0, p1);
                uu.y = pack_bf16x2(p2, p3);
                *(uint2*)&Pw[(size_t)(qn * 16 + c) * LDP + mb * 16 + g * 4] = uu;
            }
            lt += __shfl_xor(lt, 16, 64);
            lt += __shfl_xor(lt, 32, 64);
            l_r[qn] += lt;
        }

        // --- phase 5: PV MFMAs (P from LDS, V from registers) ---
#pragma unroll
        for (int ks = 0; ks < 4; ++ks) {
            bf16x8 aP0 = *(const bf16x8*)&Pw[(size_t)(c) * LDP + ks * 32 + g * 8];
            bf16x8 aP1 = *(const bf16x8*)&Pw[(size_t)(16 + c) * LDP + ks * 32 + g * 8];
#pragma unroll
            for (int nb = 0; nb < 4; ++nb) {
                O[0][nb] = MFMA16(aP0, bV[ks][nb], O[0][nb]);
                O[1][nb] = MFMA16(aP1, bV[ks][nb], O[1][nb]);
            }
        }
    }
    if (g == 0) { l_s[w][c] = l_r[0]; l_s[w][16 + c] = l_r[1]; }
    f32x4 li0 = *(f32x4*)&l_s[w][g * 4];
    f32x4 li1 = *(f32x4*)&l_s[w][16 + g * 4];
    float inv0[4], inv1[4];
#pragma unroll
    for (int r = 0; r < 4; ++r) { inv0[r] = 1.f / li0[r]; inv1[r] = 1.f / li1[r]; }
    // FB attb store: rowblk = (b*1024+qt0+w*32)/16; O[0] -> rowblk, O[1] -> +1
    int rowblk = (b * 1024 + qt0 + w * 32) >> 4;
    float psum = 0.f, psumsq = 0.f;
#pragma unroll
    for (int r = 0; r < 4; ++r) {
        int cl = g * 4 + r;                        // row%16 within chunk
#pragma unroll
        for (int nb = 0; nb < 4; ++nb) {
            float o0 = O[0][nb][r] * inv0[r];
            float o1 = O[1][nb][r] * inv1[r];
            psum += o0 + o1;
            psumsq += o0 * o0 + o1 * o1;
            int kh = nb >> 1, gb = (nb & 1) * 2 + (c >> 3), e = c & 7;
            size_t a0 = (((size_t)h * 512 + rowblk) * 2 + kh) * 512
                        + (gb * 16 + cl) * 8 + e;
            size_t a1 = (((size_t)h * 512 + rowblk + 1) * 2 + kh) * 512
                        + (gb * 16 + cl) * 8 + e;
            attb[a0] = bf16_rne(o0);
            attb[a1] = bf16_rne(o1);
        }
    }
    // fused stats1: this block covers exactly (b, h, qt0..qt0+127)
    psum = wave_sum64(psum); psumsq = wave_sum64(psumsq);
    if (lane == 0) { sbuf[w] = psum; sbuf[4 + w] = psumsq; }
    __syncthreads();
    if (tid == 0) {
        int idx = ((b * 12 + h) * 8 + qtile) * 2;
        spart[idx]     = sbuf[0] + sbuf[1] + sbuf[2] + sbuf[3];
        spart[idx + 1] = sbuf[4] + sbuf[5] + sbuf[6] + sbuf[7];
    }
}

// ---------------- stats phase 2: att -= M*a - b (attb in FB layout) ----------
__global__ __launch_bounds__(NTHREADS) void stats2_k(
    unsigned short* __restrict__ attb, const unsigned short* __restrict__ zb,
    const float* __restrict__ spart, const float* __restrict__ zpart)
{
    int blk = blockIdx.x;
    int bh = blk >> 3, ch = blk & 7;
    int b = bh / 12, h = bh % 12;
    float zs = 0.f, zs2 = 0.f, rs = 0.f, rs2 = 0.f;
#pragma unroll
    for (int cc = 0; cc < 32; ++cc) {
        zs  += zpart[(h * 32 + cc) * 2];
        zs2 += zpart[(h * 32 + cc) * 2 + 1];
    }
#pragma unroll
    for (int cc = 0; cc < 8; ++cc) {
        rs  += spart[(bh * 8 + cc) * 2];
        rs2 += spart[(bh * 8 + cc) * 2 + 1];
    }
    float m_mean = zs * (1.f / 65536.f);
    float m_var  = (zs2 - 65536.f * m_mean * m_mean) * (1.f / 65535.f);
    float m_sd   = sqrtf(fmaxf(m_var, 0.f));
    if (m_sd == 0.f) m_sd = 1.f;
    float r_mean = rs * (1.f / 65536.f);
    float r_var  = (rs2 - 65536.f * r_mean * r_mean) * (1.f / 65535.f);
    float r_sd   = sqrtf(fmaxf(r_var, 0.f));
    float a = r_sd / m_sd;
    float bc = m_mean * a - r_mean;

    const unsigned short* zrow = zb + (size_t)h * 65536 + (size_t)ch * 8192;
    for (int f = threadIdx.x; f < 1024; f += NTHREADS) {
        int p = f >> 3, dq = (f & 7) * 8;
        int row = b * 1024 + ch * 128 + p;
        int chunk = row >> 4, cl = row & 15;
        int kh = dq >> 5, gb = (dq >> 3) & 3;
        size_t aoff = (((size_t)h * 512 + chunk) * 2 + kh) * 512 + (gb * 16 + cl) * 8;
        unsigned short* ptr = attb + aoff;
        uint4 u = *(const uint4*)ptr;
        uint4 zu = *(const uint4*)(zrow + (size_t)f * 8);
        float v0 = bfu(u.x)       - bfu(zu.x)       * a + bc;
        float v1 = bfu(u.x >> 16) - bfu(zu.x >> 16) * a + bc;
        float v2 = bfu(u.y)       - bfu(zu.y)       * a + bc;
        float v3 = bfu(u.y >> 16) - bfu(zu.y >> 16) * a + bc;
        float v4 = bfu(u.z)       - bfu(zu.z)       * a + bc;
        float v5 = bfu(u.z >> 16) - bfu(zu.z >> 16) * a + bc;
        float v6 = bfu(u.w)       - bfu(zu.w)       * a + bc;
        float v7 = bfu(u.w >> 16) - bfu(zu.w >> 16) * a + bc;
        uint4 o;
        o.x = pack_bf16x2(v0, v1);
        o.y = pack_bf16x2(v2, v3);
        o.z = pack_bf16x2(v4, v5);
        o.w = pack_bf16x2(v6, v7);
        *(uint4*)ptr = o;
    }
}

extern "C" void kernel_launch(void* const* d_in, const int* in_sizes, int n_in,
                              void* d_out, int out_size, void* d_ws, size_t ws_size,
                              hipStream_t stream) {
    const float* x  = (const float*)d_in[0];
    const float* Wq = (const float*)d_in[1];
    const float* Wk = (const float*)d_in[2];
    const float* Wv = (const float*)d_in[3];
    const float* Wp = (const float*)d_in[4];
    const float* bp = (const float*)d_in[5];
    float* out = (float*)d_out;

    float* ws    = (float*)d_ws;
    float* zpart = ws;                    // 768 f (12 rows x 32 chunks x 2)
    float* spart = zpart + 768;           // 1536 f
    unsigned short* zb   = (unsigned short*)(spart + 1536);  // 786432 us
    unsigned short* xb   = zb + 786432;    // 6291456 (FB, NC=512)
    unsigned short* wstk = xb + 6291456;   // 1179648 (FB stacked q,k,v NC=96)
    unsigned short* wpt  = wstk + 1179648; // 589824  (FB, NC=48)
    unsigned short* qbh  = wpt + 589824;   // 6291456
    unsigned short* kb2  = qbh + 6291456;  // 3145728
    unsigned short* vb2  = kb2 + 3145728;  // 3145728
    unsigned short* attb = vb2 + 3145728;  // 6291456 (FB, NC=512)

    prep_k<<<2352, NTHREADS, 0, stream>>>(x, Wq, Wk, Wv, Wp,
                                          xb, wstk, wpt, zb, zpart);
    qkv_mfma_k<<<384, 512, 0, stream>>>(xb, wstk, qbh, kb2, vb2);
    attn_mfma_k<<<768, NTHREADS, 0, stream>>>(qbh, kb2, vb2, attb, spart);
    stats2_k<<<768, NTHREADS, 0, stream>>>(attb, zb, spart, zpart);
    proj_mfma_k<<<192, 512, 0, stream>>>(attb, wpt, bp, out);
}